// Round 1
// baseline (32.895 us; speedup 1.0000x reference)
//
#include <hip/hip_runtime.h>
#include <hip/hip_bf16.h>

#define LOG_2PI_HALF 0.9189385332046727f

// Each thread processes 4 rows:
//   preds: 4x float4 loads (rows 4t..4t+3), truth: 1x float4, out: 1x float4.
// All accesses are 16B/lane, fully coalesced.
__global__ __launch_bounds__(256) void dist_loss_kernel(
    const float4* __restrict__ preds4,   // one float4 per row
    const float4* __restrict__ truth4,   // 4 rows per float4
    float4* __restrict__ out4,
    int n4)                              // number of 4-row groups
{
    int t = blockIdx.x * blockDim.x + threadIdx.x;
    if (t >= n4) return;

    float4 y4 = truth4[t];
    float4 o;

    #pragma unroll
    for (int r = 0; r < 4; ++r) {
        float4 p = preds4[4 * t + r];
        float mu1 = p.x, ls1 = p.y, mu2 = p.z, ls2 = p.w;
        float y = (r == 0) ? y4.x : (r == 1) ? y4.y : (r == 2) ? y4.z : y4.w;

        float ss   = __expf(2.0f * ls1) + __expf(2.0f * ls2);   // sigma1^2 + sigma2^2
        float mu   = mu1 + mu2;
        float logy = __logf(y);
        float d    = logy - mu;
        // -log_f = LOG_2PI_HALF + 0.5*log(ss) + log(y) + d^2 / (2*ss)
        float val  = LOG_2PI_HALF + 0.5f * __logf(ss) + logy + (d * d) / (2.0f * ss);

        if (r == 0) o.x = val; else if (r == 1) o.y = val; else if (r == 2) o.z = val; else o.w = val;
    }

    out4[t] = o;
}

// Scalar tail (not needed for B=2^23, but keeps it general).
__global__ void dist_loss_tail(const float4* __restrict__ preds4,
                               const float* __restrict__ truth,
                               float* __restrict__ out,
                               int start, int n)
{
    int i = start + blockIdx.x * blockDim.x + threadIdx.x;
    if (i >= n) return;
    float4 p = preds4[i];
    float y = truth[i];
    float ss   = __expf(2.0f * p.y) + __expf(2.0f * p.w);
    float mu   = p.x + p.z;
    float logy = __logf(y);
    float d    = logy - mu;
    out[i] = LOG_2PI_HALF + 0.5f * __logf(ss) + logy + (d * d) / (2.0f * ss);
}

extern "C" void kernel_launch(void* const* d_in, const int* in_sizes, int n_in,
                              void* d_out, int out_size, void* d_ws, size_t ws_size,
                              hipStream_t stream) {
    const float* preds = (const float*)d_in[0];   // (B,4) f32
    const float* truth = (const float*)d_in[1];   // (B,1) f32
    float* out = (float*)d_out;                   // (B,) f32

    int n  = in_sizes[1];        // B rows
    int n4 = n / 4;              // 4-row groups

    if (n4 > 0) {
        int block = 256;
        int grid  = (n4 + block - 1) / block;
        dist_loss_kernel<<<grid, block, 0, stream>>>(
            (const float4*)preds, (const float4*)truth, (float4*)out, n4);
    }
    int rem_start = n4 * 4;
    int rem = n - rem_start;
    if (rem > 0) {
        dist_loss_tail<<<(rem + 255) / 256, 256, 0, stream>>>(
            (const float4*)preds, truth, out, rem_start, n);
    }
}